// Round 20
// baseline (31.617 us; speedup 1.0000x reference)
//
#include <hip/hip_runtime.h>

// Box filter 1024x1024 constant kernel, reflect pad (pl=pt=511, pr=pb=512).
// out = KC * H(V(x)) with V-first (linearity). 2-dispatch pipeline:
//  K1 scanx (R18): 192 blocks x 512 threads, float4 loads; 4-row band sums
//     in LDS + per-column shuffle scan -> BP4[ch][257][1024].
//  K2 vslideh (R20: 8-row bands, 768 blocks): vertical sliding recurrence
//     gives u0..u7 in registers (R13-proven formulas); two batched
//     H-transforms (R19-proven 3-phase emit, 2 syncs per 4-row batch).
//     Fewer boundary rows per output: 2.75 -> 2.3 row-reads/output-row.
//    U[o] = U[o-1] + x[o+512] - x[512-o]   (1 <= o <= 510)
//    U[511] = P[1024]
//    U[o] = U[o-1] - x[o-512] + x[1534-o]  (513 <= o <= 1023)

static constexpr float KC = 2.5652997311834374e-21f;
#define IMG (1024 * 1024)

__device__ __forceinline__ float hwindow(const float* S, int o) {
    float r = 0.f;
    if (o <= 510) r += S[512 - o] - S[1];                 // left mirror
    const int b0 = o > 511 ? o - 511 : 0;                 // main
    const int b1 = o + 513 < 1024 ? o + 513 : 1024;
    r += S[b1] - S[b0];
    if (o >= 512) r += S[1023] - S[1534 - o];             // right mirror
    return r;
}

// R19-proven batched 4-row emit: phase A (4 interleaved scans) - sync -
// phase B (bases + S writes) - sync - phase C (hwindow + float4 stores).
// Back-to-back calls safe: each call's A->B sync separates its wtot writes
// from the previous call's B reads; its own A-B sync covers S reuse since
// prior C reads precede A in program order.
__device__ __forceinline__ void emit4(float4 u0, float4 u1, float4 u2, float4 u3,
                                      float (*S)[1025], float (*wtot)[4],
                                      float* oc, int O, int t) {
    const int lane = t & 63, wave = t >> 6;
    const float a0 = u0.x, a1 = a0 + u0.y, a2 = a1 + u0.z, a3 = a2 + u0.w;
    const float b0 = u1.x, b1 = b0 + u1.y, b2 = b1 + u1.z, b3 = b2 + u1.w;
    const float c0 = u2.x, c1 = c0 + u2.y, c2 = c1 + u2.z, c3 = c2 + u2.w;
    const float d0 = u3.x, d1 = d0 + u3.y, d2 = d1 + u3.z, d3 = d2 + u3.w;
    float iA = a3, iB = b3, iC = c3, iD = d3;
    #pragma unroll
    for (int off = 1; off < 64; off <<= 1) {
        float nA = __shfl_up(iA, off), nB = __shfl_up(iB, off);
        float nC = __shfl_up(iC, off), nD = __shfl_up(iD, off);
        if (lane >= off) { iA += nA; iB += nB; iC += nC; iD += nD; }
    }
    if (lane == 63) {
        wtot[0][wave] = iA; wtot[1][wave] = iB;
        wtot[2][wave] = iC; wtot[3][wave] = iD;
    }
    __syncthreads();
    float wA = 0.f, wB = 0.f, wC = 0.f, wD = 0.f;
    for (int w = 0; w < wave; ++w) {
        wA += wtot[0][w]; wB += wtot[1][w];
        wC += wtot[2][w]; wD += wtot[3][w];
    }
    const float eA = wA + iA - a3;
    const float eB = wB + iB - b3;
    const float eC = wC + iC - c3;
    const float eD = wD + iD - d3;
    S[0][4 * t + 0] = eA;      S[0][4 * t + 1] = eA + a0;
    S[0][4 * t + 2] = eA + a1; S[0][4 * t + 3] = eA + a2;
    S[1][4 * t + 0] = eB;      S[1][4 * t + 1] = eB + b0;
    S[1][4 * t + 2] = eB + b1; S[1][4 * t + 3] = eB + b2;
    S[2][4 * t + 0] = eC;      S[2][4 * t + 1] = eC + c0;
    S[2][4 * t + 2] = eC + c1; S[2][4 * t + 3] = eC + c2;
    S[3][4 * t + 0] = eD;      S[3][4 * t + 1] = eD + d0;
    S[3][4 * t + 2] = eD + d1; S[3][4 * t + 3] = eD + d2;
    if (t == 255) {
        S[0][1024] = eA + a3; S[1][1024] = eB + b3;
        S[2][1024] = eC + c3; S[3][1024] = eD + d3;
    }
    __syncthreads();
    const int ox = 4 * t;
    #pragma unroll
    for (int j = 0; j < 4; ++j) {
        float4 o;
        o.x = KC * hwindow(S[j], ox + 0);
        o.y = KC * hwindow(S[j], ox + 1);
        o.z = KC * hwindow(S[j], ox + 2);
        o.w = KC * hwindow(S[j], ox + 3);
        reinterpret_cast<float4*>(oc + (size_t)(O + j) * 1024)[t] = o;
    }
}

// ---- K1: band sums from x + per-column scan -> BP4 (R18 verbatim) ---------
// grid 192 = 6ch x 32 colslabs(32 cols), 512 threads, float4 loads
__global__ __launch_bounds__(512) void scanx_kernel(const float* __restrict__ x,
                                                    float* __restrict__ BP) {
    __shared__ float B[257][33];
    const int t = threadIdx.x;
    const int ch = blockIdx.x >> 5, cg = blockIdx.x & 31;
    const int col0 = cg * 32;
    const int c4 = t & 7, g = t >> 3;          // c4: float4-col [0,8), g: row-group [0,64)
    const float4* xc = reinterpret_cast<const float4*>(x + (size_t)ch * IMG + col0) + c4;

    #pragma unroll
    for (int i = 0; i < 4; ++i) {
        const int band = g + 64 * i;
        const float4* p = xc + (size_t)band * 4 * 256;
        const float4 r0 = p[0], r1 = p[256], r2 = p[512], r3 = p[768];
        const int cc = 4 * c4;
        B[band][cc + 0] = (r0.x + r1.x) + (r2.x + r3.x);
        B[band][cc + 1] = (r0.y + r1.y) + (r2.y + r3.y);
        B[band][cc + 2] = (r0.z + r1.z) + (r2.z + r3.z);
        B[band][cc + 3] = (r0.w + r1.w) + (r2.w + r3.w);
    }
    __syncthreads();

    const int lane = t & 63, wv = t >> 6;
    #pragma unroll
    for (int i = 0; i < 4; ++i) {
        const int cc = wv * 4 + i;
        float v0 = B[lane][cc], v1 = B[lane + 64][cc],
              v2 = B[lane + 128][cc], v3 = B[lane + 192][cc];
        float i0 = v0, i1 = v1, i2 = v2, i3 = v3;
        #pragma unroll
        for (int off = 1; off < 64; off <<= 1) {
            float n0 = __shfl_up(i0, off), n1 = __shfl_up(i1, off);
            float n2 = __shfl_up(i2, off), n3 = __shfl_up(i3, off);
            if (lane >= off) { i0 += n0; i1 += n1; i2 += n2; i3 += n3; }
        }
        const float t0 = __shfl(i0, 63), t1 = __shfl(i1, 63), t2 = __shfl(i2, 63);
        B[lane][cc]       = i0 - v0;
        B[lane + 64][cc]  = t0 + i1 - v1;
        B[lane + 128][cc] = t0 + t1 + i2 - v2;
        B[lane + 192][cc] = t0 + t1 + t2 + i3 - v3;
        if (lane == 63) B[256][cc] = t0 + t1 + t2 + i3;   // P[1024]
    }
    __syncthreads();

    float* Bp = BP + (size_t)ch * 257 * 1024 + col0;
    #pragma unroll
    for (int i = 0; i < 17; ++i) {
        const int idx = i * 512 + t;
        if (idx < 257 * 32) {
            const int k = idx >> 5, cw = idx & 31;
            Bp[(size_t)k * 1024 + cw] = B[k][cw];
        }
    }
}

// ---- K2: 8-row-band vertical slide + 2x batched emit. grid 768 ------------
// 768 = 6ch x 128 bands(8 rows)
__global__ __launch_bounds__(256) void vslideh_kernel(const float* __restrict__ x,
                                                      const float* __restrict__ BP,
                                                      float* __restrict__ out) {
    __shared__ float S[4][1025];
    __shared__ float wtot[4][4];
    const int t = threadIdx.x;
    const int ch = blockIdx.x >> 7, band = blockIdx.x & 127;
    const int O = band * 8;
    const float* xc = x + (size_t)ch * IMG;
    const float* Bc = BP + (size_t)ch * 257 * 1024;
    float* oc = out + (size_t)ch * IMG;

    #define LD4(base, row) (reinterpret_cast<const float4*>((base) + (size_t)(row) * 1024)[t])
    #define ADDSUB(d, s, arow, srow) do {                         \
        const float4 A_ = LD4(xc, arow), S_ = LD4(xc, srow);      \
        d.x = s.x + A_.x - S_.x; d.y = s.y + A_.y - S_.y;         \
        d.z = s.z + A_.z - S_.z; d.w = s.w + A_.w - S_.w; } while (0)

    float4 u0, u1, u2, u3, u4, u5, u6, u7;
    if (band < 64) {
        // u0 = U[O] = P[512-O] - P[1] + P[O+513]
        const float4 bA = LD4(Bc, (512 - O) >> 2);
        const float4 x0 = LD4(xc, 0);
        const float4 bB = LD4(Bc, (512 + O) >> 2);
        const float4 xb = LD4(xc, O + 512);
        u0.x = bA.x - x0.x + bB.x + xb.x;
        u0.y = bA.y - x0.y + bB.y + xb.y;
        u0.z = bA.z - x0.z + bB.z + xb.z;
        u0.w = bA.w - x0.w + bB.w + xb.w;
        ADDSUB(u1, u0, O + 513, 511 - O);
        ADDSUB(u2, u1, O + 514, 510 - O);
        ADDSUB(u3, u2, O + 515, 509 - O);
        ADDSUB(u4, u3, O + 516, 508 - O);
        ADDSUB(u5, u4, O + 517, 507 - O);
        ADDSUB(u6, u5, O + 518, 506 - O);
        if (band == 63) {
            u7 = LD4(Bc, 256);                   // U[511] = P[1024]
        } else {
            ADDSUB(u7, u6, O + 519, 505 - O);
        }
    } else {
        // init U[O-1] = P[1024] - P[O-512] + P[1023] - P[1535-O]
        const float4 bt = LD4(Bc, 256);
        const float4 bA = LD4(Bc, (O - 512) >> 2);
        const float4 xm = LD4(xc, 1023);
        const float4 bB = LD4(Bc, (1536 - O) >> 2);
        const float4 xf = LD4(xc, 1535 - O);
        float4 acc;
        acc.x = bt.x - bA.x + (bt.x - xm.x) - (bB.x - xf.x);
        acc.y = bt.y - bA.y + (bt.y - xm.y) - (bB.y - xf.y);
        acc.z = bt.z - bA.z + (bt.z - xm.z) - (bB.z - xf.z);
        acc.w = bt.w - bA.w + (bt.w - xm.w) - (bB.w - xf.w);
        ADDSUB(u0, acc, 1534 - O, O - 512);
        ADDSUB(u1, u0, 1533 - O, O - 511);
        ADDSUB(u2, u1, 1532 - O, O - 510);
        ADDSUB(u3, u2, 1531 - O, O - 509);
        ADDSUB(u4, u3, 1530 - O, O - 508);
        ADDSUB(u5, u4, 1529 - O, O - 507);
        ADDSUB(u6, u5, 1528 - O, O - 506);
        ADDSUB(u7, u6, 1527 - O, O - 505);
    }
    #undef ADDSUB
    #undef LD4

    emit4(u0, u1, u2, u3, S, wtot, oc, O, t);
    emit4(u4, u5, u6, u7, S, wtot, oc, O + 4, t);
}

extern "C" void kernel_launch(void* const* d_in, const int* in_sizes, int n_in,
                              void* d_out, int out_size, void* d_ws, size_t ws_size,
                              hipStream_t stream) {
    const float* x = (const float*)d_in[2];
    float* out = (float*)d_out;
    float* BP = (float*)d_ws;                        // 6*257*1024 floats
    scanx_kernel<<<192, 512, 0, stream>>>(x, BP);
    vslideh_kernel<<<768, 256, 0, stream>>>(x, BP, out);
}

// Round 21
// 28.060 us; speedup vs baseline: 1.1268x; 1.1268x over previous
//
#include <hip/hip_runtime.h>

// Box filter 1024x1024 constant kernel, reflect pad (pl=pt=511, pr=pb=512).
// out = KC * H(V(x)) with V-first (linearity). 2-dispatch pipeline:
//  K1 scanx (R18): 192 blocks x 512 threads, float4 loads; 4-row band sums
//     in LDS + per-column shuffle scan -> BP4[ch][257][1024].
//  K2 vslideh (R19 + XCD swizzle): per (ch, 4-row band): vertical sliding
//     recurrence gives u0..u3 in registers; one batched 3-phase H-transform
//     (2 syncs). NEW: bijective block swizzle swz=(b&7)*192+(b>>3) makes
//     each XCD's 192 blocks channel-contiguous -> per-XCD working set ~4MB
//     (one channel) fits the 4MiB L2 instead of thrashing across 6 channels.
//    U[o] = U[o-1] + x[o+512] - x[512-o]   (1 <= o <= 510)
//    U[511] = P[1024]
//    U[o] = U[o-1] - x[o-512] + x[1534-o]  (513 <= o <= 1023)

static constexpr float KC = 2.5652997311834374e-21f;
#define IMG (1024 * 1024)

__device__ __forceinline__ float hwindow(const float* S, int o) {
    float r = 0.f;
    if (o <= 510) r += S[512 - o] - S[1];                 // left mirror
    const int b0 = o > 511 ? o - 511 : 0;                 // main
    const int b1 = o + 513 < 1024 ? o + 513 : 1024;
    r += S[b1] - S[b0];
    if (o >= 512) r += S[1023] - S[1534 - o];             // right mirror
    return r;
}

// ---- K1: band sums from x + per-column scan -> BP4 (R18 verbatim) ---------
// grid 192 = 6ch x 32 colslabs(32 cols), 512 threads, float4 loads
__global__ __launch_bounds__(512) void scanx_kernel(const float* __restrict__ x,
                                                    float* __restrict__ BP) {
    __shared__ float B[257][33];
    const int t = threadIdx.x;
    const int ch = blockIdx.x >> 5, cg = blockIdx.x & 31;
    const int col0 = cg * 32;
    const int c4 = t & 7, g = t >> 3;          // c4: float4-col [0,8), g: row-group [0,64)
    const float4* xc = reinterpret_cast<const float4*>(x + (size_t)ch * IMG + col0) + c4;

    #pragma unroll
    for (int i = 0; i < 4; ++i) {
        const int band = g + 64 * i;
        const float4* p = xc + (size_t)band * 4 * 256;
        const float4 r0 = p[0], r1 = p[256], r2 = p[512], r3 = p[768];
        const int cc = 4 * c4;
        B[band][cc + 0] = (r0.x + r1.x) + (r2.x + r3.x);
        B[band][cc + 1] = (r0.y + r1.y) + (r2.y + r3.y);
        B[band][cc + 2] = (r0.z + r1.z) + (r2.z + r3.z);
        B[band][cc + 3] = (r0.w + r1.w) + (r2.w + r3.w);
    }
    __syncthreads();

    const int lane = t & 63, wv = t >> 6;
    #pragma unroll
    for (int i = 0; i < 4; ++i) {
        const int cc = wv * 4 + i;
        float v0 = B[lane][cc], v1 = B[lane + 64][cc],
              v2 = B[lane + 128][cc], v3 = B[lane + 192][cc];
        float i0 = v0, i1 = v1, i2 = v2, i3 = v3;
        #pragma unroll
        for (int off = 1; off < 64; off <<= 1) {
            float n0 = __shfl_up(i0, off), n1 = __shfl_up(i1, off);
            float n2 = __shfl_up(i2, off), n3 = __shfl_up(i3, off);
            if (lane >= off) { i0 += n0; i1 += n1; i2 += n2; i3 += n3; }
        }
        const float t0 = __shfl(i0, 63), t1 = __shfl(i1, 63), t2 = __shfl(i2, 63);
        B[lane][cc]       = i0 - v0;
        B[lane + 64][cc]  = t0 + i1 - v1;
        B[lane + 128][cc] = t0 + t1 + i2 - v2;
        B[lane + 192][cc] = t0 + t1 + t2 + i3 - v3;
        if (lane == 63) B[256][cc] = t0 + t1 + t2 + i3;   // P[1024]
    }
    __syncthreads();

    float* Bp = BP + (size_t)ch * 257 * 1024 + col0;
    #pragma unroll
    for (int i = 0; i < 17; ++i) {
        const int idx = i * 512 + t;
        if (idx < 257 * 32) {
            const int k = idx >> 5, cw = idx & 31;
            Bp[(size_t)k * 1024 + cw] = B[k][cw];
        }
    }
}

// ---- K2: vertical slide + batched in-block horizontal. grid 1536 ----------
// XCD-swizzled: swz = (b&7)*192 + (b>>3) (bijective, 1536%8==0) so each
// XCD's blocks are channel-contiguous (L2-resident working set).
__global__ __launch_bounds__(256) void vslideh_kernel(const float* __restrict__ x,
                                                      const float* __restrict__ BP,
                                                      float* __restrict__ out) {
    __shared__ float S[4][1025];
    __shared__ float wtot[4][4];
    const int t = threadIdx.x;
    const int swz = (blockIdx.x & 7) * 192 + (blockIdx.x >> 3);
    const int ch = swz >> 8, band = swz & 255;
    const int O = band * 4;
    const float* xc = x + (size_t)ch * IMG;
    const float* Bc = BP + (size_t)ch * 257 * 1024;
    float* oc = out + (size_t)ch * IMG;

    #define LD4(base, row) (reinterpret_cast<const float4*>((base) + (size_t)(row) * 1024)[t])

    // ---- u0..u3 (R14-proven construction) ----
    float4 u0, u1, u2, u3;
    if (band < 128) {
        const float4 bA = LD4(Bc, (512 - O) >> 2);
        const float4 x0 = LD4(xc, 0);
        const float4 bB = LD4(Bc, (512 + O) >> 2);
        const float4 xb = LD4(xc, O + 512);
        u0.x = bA.x - x0.x + bB.x + xb.x;
        u0.y = bA.y - x0.y + bB.y + xb.y;
        u0.z = bA.z - x0.z + bB.z + xb.z;
        u0.w = bA.w - x0.w + bB.w + xb.w;
        {
            const float4 a = LD4(xc, O + 513), s = LD4(xc, 511 - O);
            u1.x = u0.x + a.x - s.x; u1.y = u0.y + a.y - s.y;
            u1.z = u0.z + a.z - s.z; u1.w = u0.w + a.w - s.w;
        }
        {
            const float4 a = LD4(xc, O + 514), s = LD4(xc, 510 - O);
            u2.x = u1.x + a.x - s.x; u2.y = u1.y + a.y - s.y;
            u2.z = u1.z + a.z - s.z; u2.w = u1.w + a.w - s.w;
        }
        if (band == 127) {
            u3 = LD4(Bc, 256);                       // U[511] = P[1024]
        } else {
            const float4 a = LD4(xc, O + 515), s = LD4(xc, 509 - O);
            u3.x = u2.x + a.x - s.x; u3.y = u2.y + a.y - s.y;
            u3.z = u2.z + a.z - s.z; u3.w = u2.w + a.w - s.w;
        }
    } else {
        const float4 bt = LD4(Bc, 256);
        const float4 bA = LD4(Bc, (O - 512) >> 2);
        const float4 xm = LD4(xc, 1023);
        const float4 bB = LD4(Bc, (1536 - O) >> 2);
        const float4 xf = LD4(xc, 1535 - O);
        float4 acc;
        acc.x = bt.x - bA.x + (bt.x - xm.x) - (bB.x - xf.x);
        acc.y = bt.y - bA.y + (bt.y - xm.y) - (bB.y - xf.y);
        acc.z = bt.z - bA.z + (bt.z - xm.z) - (bB.z - xf.z);
        acc.w = bt.w - bA.w + (bt.w - xm.w) - (bB.w - xf.w);
        {
            const float4 a = LD4(xc, 1534 - O), s = LD4(xc, O - 512);
            u0.x = acc.x + a.x - s.x; u0.y = acc.y + a.y - s.y;
            u0.z = acc.z + a.z - s.z; u0.w = acc.w + a.w - s.w;
        }
        {
            const float4 a = LD4(xc, 1533 - O), s = LD4(xc, O - 511);
            u1.x = u0.x + a.x - s.x; u1.y = u0.y + a.y - s.y;
            u1.z = u0.z + a.z - s.z; u1.w = u0.w + a.w - s.w;
        }
        {
            const float4 a = LD4(xc, 1532 - O), s = LD4(xc, O - 510);
            u2.x = u1.x + a.x - s.x; u2.y = u1.y + a.y - s.y;
            u2.z = u1.z + a.z - s.z; u2.w = u1.w + a.w - s.w;
        }
        {
            const float4 a = LD4(xc, 1531 - O), s = LD4(xc, O - 509);
            u3.x = u2.x + a.x - s.x; u3.y = u2.y + a.y - s.y;
            u3.z = u2.z + a.z - s.z; u3.w = u2.w + a.w - s.w;
        }
    }
    #undef LD4

    const int lane = t & 63, wave = t >> 6;

    // ---- phase A: 4 interleaved block scans ----
    const float a0 = u0.x, a1 = a0 + u0.y, a2 = a1 + u0.z, a3 = a2 + u0.w;
    const float b0 = u1.x, b1 = b0 + u1.y, b2 = b1 + u1.z, b3 = b2 + u1.w;
    const float c0 = u2.x, c1 = c0 + u2.y, c2 = c1 + u2.z, c3 = c2 + u2.w;
    const float d0 = u3.x, d1 = d0 + u3.y, d2 = d1 + u3.z, d3 = d2 + u3.w;
    float iA = a3, iB = b3, iC = c3, iD = d3;
    #pragma unroll
    for (int off = 1; off < 64; off <<= 1) {
        float nA = __shfl_up(iA, off), nB = __shfl_up(iB, off);
        float nC = __shfl_up(iC, off), nD = __shfl_up(iD, off);
        if (lane >= off) { iA += nA; iB += nB; iC += nC; iD += nD; }
    }
    if (lane == 63) {
        wtot[0][wave] = iA; wtot[1][wave] = iB;
        wtot[2][wave] = iC; wtot[3][wave] = iD;
    }
    __syncthreads();

    // ---- phase B: bases + S writes for all 4 rows ----
    float wA = 0.f, wB = 0.f, wC = 0.f, wD = 0.f;
    for (int w = 0; w < wave; ++w) {
        wA += wtot[0][w]; wB += wtot[1][w];
        wC += wtot[2][w]; wD += wtot[3][w];
    }
    const float eA = wA + iA - a3;
    const float eB = wB + iB - b3;
    const float eC = wC + iC - c3;
    const float eD = wD + iD - d3;
    S[0][4 * t + 0] = eA;      S[0][4 * t + 1] = eA + a0;
    S[0][4 * t + 2] = eA + a1; S[0][4 * t + 3] = eA + a2;
    S[1][4 * t + 0] = eB;      S[1][4 * t + 1] = eB + b0;
    S[1][4 * t + 2] = eB + b1; S[1][4 * t + 3] = eB + b2;
    S[2][4 * t + 0] = eC;      S[2][4 * t + 1] = eC + c0;
    S[2][4 * t + 2] = eC + c1; S[2][4 * t + 3] = eC + c2;
    S[3][4 * t + 0] = eD;      S[3][4 * t + 1] = eD + d0;
    S[3][4 * t + 2] = eD + d1; S[3][4 * t + 3] = eD + d2;
    if (t == 255) {
        S[0][1024] = eA + a3; S[1][1024] = eB + b3;
        S[2][1024] = eC + c3; S[3][1024] = eD + d3;
    }
    __syncthreads();

    // ---- phase C: hwindow + stores for all 4 rows ----
    const int ox = 4 * t;
    #pragma unroll
    for (int j = 0; j < 4; ++j) {
        float4 o;
        o.x = KC * hwindow(S[j], ox + 0);
        o.y = KC * hwindow(S[j], ox + 1);
        o.z = KC * hwindow(S[j], ox + 2);
        o.w = KC * hwindow(S[j], ox + 3);
        reinterpret_cast<float4*>(oc + (size_t)(O + j) * 1024)[t] = o;
    }
}

extern "C" void kernel_launch(void* const* d_in, const int* in_sizes, int n_in,
                              void* d_out, int out_size, void* d_ws, size_t ws_size,
                              hipStream_t stream) {
    const float* x = (const float*)d_in[2];
    float* out = (float*)d_out;
    float* BP = (float*)d_ws;                        // 6*257*1024 floats
    scanx_kernel<<<192, 512, 0, stream>>>(x, BP);
    vslideh_kernel<<<1536, 256, 0, stream>>>(x, BP, out);
}

// Round 22
// 27.434 us; speedup vs baseline: 1.1525x; 1.0228x over previous
//
#include <hip/hip_runtime.h>

// Box filter 1024x1024 constant kernel, reflect pad (pl=pt=511, pr=pb=512).
// out = KC * H(V(x)) with V-first (linearity). 2-dispatch pipeline:
//  K1 scanx (R18): 192 blocks x 512 threads, float4 loads; 4-row band sums
//     in LDS + per-column shuffle scan -> BP4[ch][257][1024].
//  K2 vslideh (R21 + PADDED-S): per (ch, 4-row band): vertical sliding
//     recurrence gives u0..u3; one batched 3-phase H-transform (2 syncs),
//     XCD swizzle swz=(b&7)*192+(b>>3). NEW: S stored padded at
//     SI(o)=o+(o>>5) so the stride-4 lane access pattern in phases B/C hits
//     all 32 banks 2-way (free, m136) instead of 8 banks 8-way (2.94x).
//    U[o] = U[o-1] + x[o+512] - x[512-o]   (1 <= o <= 510)
//    U[511] = P[1024]
//    U[o] = U[o-1] - x[o-512] + x[1534-o]  (513 <= o <= 1023)

static constexpr float KC = 2.5652997311834374e-21f;
#define IMG (1024 * 1024)
#define SI(o) ((o) + ((o) >> 5))          // padded LDS index: bank-spread
#define SLEN 1057                         // SI(1024) = 1056

__device__ __forceinline__ float hwindow_p(const float* S, int o) {
    float r = 0.f;
    if (o <= 510) r += S[SI(512 - o)] - S[SI(1)];         // left mirror
    const int b0 = o > 511 ? o - 511 : 0;                 // main
    const int b1 = o + 513 < 1024 ? o + 513 : 1024;
    r += S[SI(b1)] - S[SI(b0)];
    if (o >= 512) r += S[SI(1023)] - S[SI(1534 - o)];     // right mirror
    return r;
}

// ---- K1: band sums from x + per-column scan -> BP4 (R18 verbatim) ---------
// grid 192 = 6ch x 32 colslabs(32 cols), 512 threads, float4 loads
__global__ __launch_bounds__(512) void scanx_kernel(const float* __restrict__ x,
                                                    float* __restrict__ BP) {
    __shared__ float B[257][33];
    const int t = threadIdx.x;
    const int ch = blockIdx.x >> 5, cg = blockIdx.x & 31;
    const int col0 = cg * 32;
    const int c4 = t & 7, g = t >> 3;          // c4: float4-col [0,8), g: row-group [0,64)
    const float4* xc = reinterpret_cast<const float4*>(x + (size_t)ch * IMG + col0) + c4;

    #pragma unroll
    for (int i = 0; i < 4; ++i) {
        const int band = g + 64 * i;
        const float4* p = xc + (size_t)band * 4 * 256;
        const float4 r0 = p[0], r1 = p[256], r2 = p[512], r3 = p[768];
        const int cc = 4 * c4;
        B[band][cc + 0] = (r0.x + r1.x) + (r2.x + r3.x);
        B[band][cc + 1] = (r0.y + r1.y) + (r2.y + r3.y);
        B[band][cc + 2] = (r0.z + r1.z) + (r2.z + r3.z);
        B[band][cc + 3] = (r0.w + r1.w) + (r2.w + r3.w);
    }
    __syncthreads();

    const int lane = t & 63, wv = t >> 6;
    #pragma unroll
    for (int i = 0; i < 4; ++i) {
        const int cc = wv * 4 + i;
        float v0 = B[lane][cc], v1 = B[lane + 64][cc],
              v2 = B[lane + 128][cc], v3 = B[lane + 192][cc];
        float i0 = v0, i1 = v1, i2 = v2, i3 = v3;
        #pragma unroll
        for (int off = 1; off < 64; off <<= 1) {
            float n0 = __shfl_up(i0, off), n1 = __shfl_up(i1, off);
            float n2 = __shfl_up(i2, off), n3 = __shfl_up(i3, off);
            if (lane >= off) { i0 += n0; i1 += n1; i2 += n2; i3 += n3; }
        }
        const float t0 = __shfl(i0, 63), t1 = __shfl(i1, 63), t2 = __shfl(i2, 63);
        B[lane][cc]       = i0 - v0;
        B[lane + 64][cc]  = t0 + i1 - v1;
        B[lane + 128][cc] = t0 + t1 + i2 - v2;
        B[lane + 192][cc] = t0 + t1 + t2 + i3 - v3;
        if (lane == 63) B[256][cc] = t0 + t1 + t2 + i3;   // P[1024]
    }
    __syncthreads();

    float* Bp = BP + (size_t)ch * 257 * 1024 + col0;
    #pragma unroll
    for (int i = 0; i < 17; ++i) {
        const int idx = i * 512 + t;
        if (idx < 257 * 32) {
            const int k = idx >> 5, cw = idx & 31;
            Bp[(size_t)k * 1024 + cw] = B[k][cw];
        }
    }
}

// ---- K2: vertical slide + batched in-block horizontal. grid 1536 ----------
__global__ __launch_bounds__(256) void vslideh_kernel(const float* __restrict__ x,
                                                      const float* __restrict__ BP,
                                                      float* __restrict__ out) {
    __shared__ float S[4][SLEN];
    __shared__ float wtot[4][4];
    const int t = threadIdx.x;
    const int swz = (blockIdx.x & 7) * 192 + (blockIdx.x >> 3);
    const int ch = swz >> 8, band = swz & 255;
    const int O = band * 4;
    const float* xc = x + (size_t)ch * IMG;
    const float* Bc = BP + (size_t)ch * 257 * 1024;
    float* oc = out + (size_t)ch * IMG;

    #define LD4(base, row) (reinterpret_cast<const float4*>((base) + (size_t)(row) * 1024)[t])

    // ---- u0..u3 (R14-proven construction) ----
    float4 u0, u1, u2, u3;
    if (band < 128) {
        const float4 bA = LD4(Bc, (512 - O) >> 2);
        const float4 x0 = LD4(xc, 0);
        const float4 bB = LD4(Bc, (512 + O) >> 2);
        const float4 xb = LD4(xc, O + 512);
        u0.x = bA.x - x0.x + bB.x + xb.x;
        u0.y = bA.y - x0.y + bB.y + xb.y;
        u0.z = bA.z - x0.z + bB.z + xb.z;
        u0.w = bA.w - x0.w + bB.w + xb.w;
        {
            const float4 a = LD4(xc, O + 513), s = LD4(xc, 511 - O);
            u1.x = u0.x + a.x - s.x; u1.y = u0.y + a.y - s.y;
            u1.z = u0.z + a.z - s.z; u1.w = u0.w + a.w - s.w;
        }
        {
            const float4 a = LD4(xc, O + 514), s = LD4(xc, 510 - O);
            u2.x = u1.x + a.x - s.x; u2.y = u1.y + a.y - s.y;
            u2.z = u1.z + a.z - s.z; u2.w = u1.w + a.w - s.w;
        }
        if (band == 127) {
            u3 = LD4(Bc, 256);                       // U[511] = P[1024]
        } else {
            const float4 a = LD4(xc, O + 515), s = LD4(xc, 509 - O);
            u3.x = u2.x + a.x - s.x; u3.y = u2.y + a.y - s.y;
            u3.z = u2.z + a.z - s.z; u3.w = u2.w + a.w - s.w;
        }
    } else {
        const float4 bt = LD4(Bc, 256);
        const float4 bA = LD4(Bc, (O - 512) >> 2);
        const float4 xm = LD4(xc, 1023);
        const float4 bB = LD4(Bc, (1536 - O) >> 2);
        const float4 xf = LD4(xc, 1535 - O);
        float4 acc;
        acc.x = bt.x - bA.x + (bt.x - xm.x) - (bB.x - xf.x);
        acc.y = bt.y - bA.y + (bt.y - xm.y) - (bB.y - xf.y);
        acc.z = bt.z - bA.z + (bt.z - xm.z) - (bB.z - xf.z);
        acc.w = bt.w - bA.w + (bt.w - xm.w) - (bB.w - xf.w);
        {
            const float4 a = LD4(xc, 1534 - O), s = LD4(xc, O - 512);
            u0.x = acc.x + a.x - s.x; u0.y = acc.y + a.y - s.y;
            u0.z = acc.z + a.z - s.z; u0.w = acc.w + a.w - s.w;
        }
        {
            const float4 a = LD4(xc, 1533 - O), s = LD4(xc, O - 511);
            u1.x = u0.x + a.x - s.x; u1.y = u0.y + a.y - s.y;
            u1.z = u0.z + a.z - s.z; u1.w = u0.w + a.w - s.w;
        }
        {
            const float4 a = LD4(xc, 1532 - O), s = LD4(xc, O - 510);
            u2.x = u1.x + a.x - s.x; u2.y = u1.y + a.y - s.y;
            u2.z = u1.z + a.z - s.z; u2.w = u1.w + a.w - s.w;
        }
        {
            const float4 a = LD4(xc, 1531 - O), s = LD4(xc, O - 509);
            u3.x = u2.x + a.x - s.x; u3.y = u2.y + a.y - s.y;
            u3.z = u2.z + a.z - s.z; u3.w = u2.w + a.w - s.w;
        }
    }
    #undef LD4

    const int lane = t & 63, wave = t >> 6;

    // ---- phase A: 4 interleaved block scans ----
    const float a0 = u0.x, a1 = a0 + u0.y, a2 = a1 + u0.z, a3 = a2 + u0.w;
    const float b0 = u1.x, b1 = b0 + u1.y, b2 = b1 + u1.z, b3 = b2 + u1.w;
    const float c0 = u2.x, c1 = c0 + u2.y, c2 = c1 + u2.z, c3 = c2 + u2.w;
    const float d0 = u3.x, d1 = d0 + u3.y, d2 = d1 + u3.z, d3 = d2 + u3.w;
    float iA = a3, iB = b3, iC = c3, iD = d3;
    #pragma unroll
    for (int off = 1; off < 64; off <<= 1) {
        float nA = __shfl_up(iA, off), nB = __shfl_up(iB, off);
        float nC = __shfl_up(iC, off), nD = __shfl_up(iD, off);
        if (lane >= off) { iA += nA; iB += nB; iC += nC; iD += nD; }
    }
    if (lane == 63) {
        wtot[0][wave] = iA; wtot[1][wave] = iB;
        wtot[2][wave] = iC; wtot[3][wave] = iD;
    }
    __syncthreads();

    // ---- phase B: bases + padded S writes for all 4 rows ----
    float wA = 0.f, wB = 0.f, wC = 0.f, wD = 0.f;
    for (int w = 0; w < wave; ++w) {
        wA += wtot[0][w]; wB += wtot[1][w];
        wC += wtot[2][w]; wD += wtot[3][w];
    }
    const float eA = wA + iA - a3;
    const float eB = wB + iB - b3;
    const float eC = wC + iC - c3;
    const float eD = wD + iD - d3;
    const int ox = 4 * t;
    S[0][SI(ox + 0)] = eA;      S[0][SI(ox + 1)] = eA + a0;
    S[0][SI(ox + 2)] = eA + a1; S[0][SI(ox + 3)] = eA + a2;
    S[1][SI(ox + 0)] = eB;      S[1][SI(ox + 1)] = eB + b0;
    S[1][SI(ox + 2)] = eB + b1; S[1][SI(ox + 3)] = eB + b2;
    S[2][SI(ox + 0)] = eC;      S[2][SI(ox + 1)] = eC + c0;
    S[2][SI(ox + 2)] = eC + c1; S[2][SI(ox + 3)] = eC + c2;
    S[3][SI(ox + 0)] = eD;      S[3][SI(ox + 1)] = eD + d0;
    S[3][SI(ox + 2)] = eD + d1; S[3][SI(ox + 3)] = eD + d2;
    if (t == 255) {
        S[0][SI(1024)] = eA + a3; S[1][SI(1024)] = eB + b3;
        S[2][SI(1024)] = eC + c3; S[3][SI(1024)] = eD + d3;
    }
    __syncthreads();

    // ---- phase C: hwindow + float4 stores for all 4 rows ----
    #pragma unroll
    for (int j = 0; j < 4; ++j) {
        float4 o;
        o.x = KC * hwindow_p(S[j], ox + 0);
        o.y = KC * hwindow_p(S[j], ox + 1);
        o.z = KC * hwindow_p(S[j], ox + 2);
        o.w = KC * hwindow_p(S[j], ox + 3);
        reinterpret_cast<float4*>(oc + (size_t)(O + j) * 1024)[t] = o;
    }
}

extern "C" void kernel_launch(void* const* d_in, const int* in_sizes, int n_in,
                              void* d_out, int out_size, void* d_ws, size_t ws_size,
                              hipStream_t stream) {
    const float* x = (const float*)d_in[2];
    float* out = (float*)d_out;
    float* BP = (float*)d_ws;                        // 6*257*1024 floats
    scanx_kernel<<<192, 512, 0, stream>>>(x, BP);
    vslideh_kernel<<<1536, 256, 0, stream>>>(x, BP, out);
}